// Round 4
// baseline (2720.939 us; speedup 1.0000x reference)
//
#include <hip/hip_runtime.h>

// CorrNeigh: out[b, i*7+j, h, w] = sum_c x[b,c,h,w] * y[b,c,h+i-3,w+j-3]
// B=8 C=128 H=W=256, K=7, PAD=3, fp32.
//
// Round 4: latency-bound fix (R3: VALUBusy 30%, HBM 12%).
//  - No LDS, no shfl, no masks in the hot loop. Each lane loads its own
//    aligned y octet (2x float4) plus left/right halo quads (overlapping
//    neighbor data; L1 serves the overlap). Pad semantics handled ONCE in
//    the prologue: invalid pointers are redirected to a 256B zeroed region
//    of d_ws with per-lane channel-stride 0, so loaded values are
//    correct-or-zero with no per-iteration masking.
//  - 2-stage software pipeline, channel loop unrolled x2: issue c+2/c+3's
//    6 loads while computing c/c+1 -> 6-12 dwordx4 in flight per wave.
//  - __launch_bounds__(448,4): 128-VGPR cap fits acc(56)+2x24 load regs,
//    avoids the 56-VGPR/AGPR-thrash regime R3 landed in.
//  - Block = 7 waves, wave i = dy; lane owns 8 w-consecutive pixels of a
//    64x8 tile; 56 FMA per lane per channel.
//  - XCD-chunked swizzle: one batch image per XCD.

#define Bq 8
#define Cq 128
#define Hq 256
#define Wq 256
#define Kq 7
#define TILE_H 8
#define TILE_W 64
#define NTHR 448
#define CS (Hq * Wq)

__global__ __launch_bounds__(NTHR, 4)
void corr7_kernel(const float* __restrict__ x, const float* __restrict__ y,
                  float* __restrict__ out, const float* __restrict__ zbuf)
{
    const int t    = threadIdx.x;
    const int wave = t >> 6;        // dy index i (0..6)
    const int lane = t & 63;
    const int lw   = lane & 7;      // w-octet
    const int lr   = lane >> 3;     // row within tile (0..7)

    // XCD-chunked swizzle: XCD k gets tiles [k*128, (k+1)*128) = one batch image
    int bid = (int)blockIdx.x;
    bid = (bid & 7) * 128 + (bid >> 3);
    const int tw = bid & 3;
    const int th = (bid >> 2) & 31;
    const int b  = bid >> 7;

    const int h0 = th * TILE_H;
    const int w0 = tw * TILE_W;

    const size_t base = (size_t)b * Cq * CS;

    // validity of this lane's y row / halo quads (pad -> zbuf, stride 0)
    const int gy  = h0 + lr + wave - 3;
    const bool vo = ((unsigned)gy < (unsigned)Hq);
    const bool vl = vo && !(tw == 0 && lw == 0);
    const bool vr = vo && !(tw == 3 && lw == 7);

    const float* yrow = y + base + (size_t)(vo ? gy : 0) * Wq;

    // A-set pointers start at channel 0, B-set at channel 1; each bumps 2*CS.
    const float* Ax  = x + base + (size_t)(h0 + lr) * Wq + (w0 + 8 * lw);
    const float* Ay0 = vo ? (yrow + w0 + 8 * lw)     : zbuf;
    const float* Ayl = vl ? (yrow + w0 + 8 * lw - 4) : zbuf;
    const float* Ayr = vr ? (yrow + w0 + 8 * lw + 8) : zbuf;

    const unsigned sx = 2u * CS;
    const unsigned so = vo ? 2u * CS : 0u;
    const unsigned sl = vl ? 2u * CS : 0u;
    const unsigned sr = vr ? 2u * CS : 0u;

    const float* Bx  = Ax + CS;
    const float* By0 = vo ? (Ay0 + CS) : zbuf;
    const float* Byl = vl ? (Ayl + CS) : zbuf;
    const float* Byr = vr ? (Ayr + CS) : zbuf;

    float acc[Kq][8];
#pragma unroll
    for (int j = 0; j < Kq; ++j)
#pragma unroll
        for (int r = 0; r < 8; ++r) acc[j][r] = 0.f;

    float4 ax0, ax1, al4, a04, a14, ar4;
    float4 bx0, bx1, bl4, b04, b14, br4;

#define ISSUE(px, pyl, py0, pyr, rx0, rx1, rl, r0, r1, rr)     \
    rx0 = *(const float4*)(px);                                \
    rx1 = *(const float4*)((px) + 4);                          \
    rl  = *(const float4*)(pyl);                               \
    r0  = *(const float4*)(py0);                               \
    r1  = *(const float4*)((py0) + 4);                         \
    rr  = *(const float4*)(pyr);                               \
    px += sx; pyl += sl; py0 += so; pyr += sr;

#define FMABLK(rx0, rx1, rl, r0, r1, rr) {                                    \
    const float yw[14] = { rl.y, rl.z, rl.w,                                  \
                           r0.x, r0.y, r0.z, r0.w,                            \
                           r1.x, r1.y, r1.z, r1.w,                            \
                           rr.x, rr.y, rr.z };                                \
    const float xv[8]  = { rx0.x, rx0.y, rx0.z, rx0.w,                        \
                           rx1.x, rx1.y, rx1.z, rx1.w };                      \
    _Pragma("unroll")                                                         \
    for (int j = 0; j < Kq; ++j)                                              \
        _Pragma("unroll")                                                     \
        for (int r = 0; r < 8; ++r)                                           \
            acc[j][r] = fmaf(xv[r], yw[r + j], acc[j][r]);                    \
}

    ISSUE(Ax, Ayl, Ay0, Ayr, ax0, ax1, al4, a04, a14, ar4)   // ch 0
    ISSUE(Bx, Byl, By0, Byr, bx0, bx1, bl4, b04, b14, br4)   // ch 1

#pragma unroll 1
    for (int c = 0; c < Cq - 2; c += 2) {
        FMABLK(ax0, ax1, al4, a04, a14, ar4)                  // consume ch c
        ISSUE(Ax, Ayl, Ay0, Ayr, ax0, ax1, al4, a04, a14, ar4) // load ch c+2
        FMABLK(bx0, bx1, bl4, b04, b14, br4)                  // consume ch c+1
        ISSUE(Bx, Byl, By0, Byr, bx0, bx1, bl4, b04, b14, br4) // load ch c+3
    }
    FMABLK(ax0, ax1, al4, a04, a14, ar4)   // ch 126
    FMABLK(bx0, bx1, bl4, b04, b14, br4)   // ch 127

#undef ISSUE
#undef FMABLK

    // epilogue: this wave writes k-planes wave*7 .. wave*7+6
    size_t obase = (((size_t)b * (Kq * Kq) + (size_t)wave * Kq) * Hq
                    + (h0 + lr)) * Wq + (w0 + 8 * lw);
#pragma unroll
    for (int j = 0; j < Kq; ++j) {
        float4 o0 = {acc[j][0], acc[j][1], acc[j][2], acc[j][3]};
        float4 o1 = {acc[j][4], acc[j][5], acc[j][6], acc[j][7]};
        *(float4*)(out + obase)     = o0;
        *(float4*)(out + obase + 4) = o1;
        obase += (size_t)CS;  // next k-plane
    }
}

extern "C" void kernel_launch(void* const* d_in, const int* in_sizes, int n_in,
                              void* d_out, int out_size, void* d_ws, size_t ws_size,
                              hipStream_t stream) {
    const float* x = (const float*)d_in[0];
    const float* y = (const float*)d_in[1];
    float* out = (float*)d_out;

    // zero pad-source region (invalid-lane pointers aim here, stride 0)
    hipMemsetAsync(d_ws, 0, 256, stream);

    dim3 grid(Bq * 32 * 4);   // 1024 tiles: 8 batches x 32 h x 4 w
    dim3 block(NTHR);
    hipLaunchKernelGGL(corr7_kernel, grid, block, 0, stream,
                       x, y, out, (const float*)d_ws);
}

// Round 5
// 424.415 us; speedup vs baseline: 6.4110x; 6.4110x over previous
//
#include <hip/hip_runtime.h>

// CorrNeigh: out[b, i*7+j, h, w] = sum_c x[b,c,h,w] * y[b,c,h+i-3,w+j-3]
// B=8 C=128 H=W=256, K=7, PAD=3, fp32.
//
// Round 5: R4's pipeline structure was right but spilled (WRITE_SIZE 6.4GB of
// scratch traffic at the 128-VGPR cap). Halve per-thread state: 4 pixels/lane
// (tile 32w x 8h), acc 7x4=28, pipeline sets 2x16 floats -> ~90 VGPR, fits
// __launch_bounds__(448,4) cap 128 with slack -> 2 blocks/CU, no scratch.
//
//  - Block = 7 waves (448 thr), wave i = dy. Lane: lw=lane&7 (w-quad),
//    lr=lane>>3 (row 0..7). Lane owns 4 w-consecutive pixels.
//  - No LDS / shfl / masks in the loop: lane loads left/own/right aligned
//    y quads (neighbor overlap -> L1) + x quad. Pad handled in prologue by
//    redirecting invalid pointers to a zeroed d_ws region with stride 0.
//  - 2-deep software pipeline (A/B channel sets), 8 dwordx4 in flight.
//  - XCD-chunked swizzle: one batch image (256 tiles) per XCD.

#define Bq 8
#define Cq 128
#define Hq 256
#define Wq 256
#define Kq 7
#define TILE_H 8
#define TILE_W 32
#define NTHR 448
#define CS (Hq * Wq)

__global__ __launch_bounds__(NTHR, 4)
void corr7_kernel(const float* __restrict__ x, const float* __restrict__ y,
                  float* __restrict__ out, const float* __restrict__ zbuf)
{
    const int t    = threadIdx.x;
    const int wave = t >> 6;        // dy index i (0..6)
    const int lane = t & 63;
    const int lw   = lane & 7;      // w-quad (8 quads x 4 = 32 cols)
    const int lr   = lane >> 3;     // row within tile (0..7)

    // XCD-chunked swizzle: XCD k gets tiles [k*256, (k+1)*256) = one image
    int bid = (int)blockIdx.x;
    bid = (bid & 7) * 256 + (bid >> 3);
    const int tw = bid & 7;          // 8 w-tiles
    const int th = (bid >> 3) & 31;  // 32 h-tiles
    const int b  = bid >> 8;         // batch

    const int h0 = th * TILE_H;
    const int w0 = tw * TILE_W;
    const int wq = w0 + 4 * lw;      // this lane's first output column

    const size_t base = (size_t)b * Cq * CS;

    // validity of this lane's y row / halo quads (invalid -> zbuf, stride 0)
    const int gy  = h0 + lr + wave - 3;
    const bool vo = ((unsigned)gy < (unsigned)Hq);
    const bool vl = vo && !(tw == 0 && lw == 0);
    const bool vr = vo && !(tw == 7 && lw == 7);

    const float* yrow = y + base + (size_t)(vo ? gy : 0) * Wq;

    // A-set at channel 0, B-set at channel 1; each bumps 2*CS (0 if invalid).
    const float* Ax  = x + base + (size_t)(h0 + lr) * Wq + wq;
    const float* Ay0 = vo ? (yrow + wq)     : zbuf;
    const float* Ayl = vl ? (yrow + wq - 4) : zbuf;
    const float* Ayr = vr ? (yrow + wq + 4) : zbuf;

    const unsigned sx = 2u * CS;
    const unsigned so = vo ? 2u * CS : 0u;
    const unsigned sl = vl ? 2u * CS : 0u;
    const unsigned sr = vr ? 2u * CS : 0u;

    const float* Bx  = Ax + CS;
    const float* By0 = vo ? (Ay0 + CS) : zbuf;
    const float* Byl = vl ? (Ayl + CS) : zbuf;
    const float* Byr = vr ? (Ayr + CS) : zbuf;

    float acc[Kq][4];
#pragma unroll
    for (int j = 0; j < Kq; ++j)
#pragma unroll
        for (int r = 0; r < 4; ++r) acc[j][r] = 0.f;

    float4 axq, alq, aoq, arq;
    float4 bxq, blq, boq, brq;

#define ISSUE(px, pyl, py0, pyr, rx, rl, r0, rr)   \
    rx = *(const float4*)(px);                     \
    rl = *(const float4*)(pyl);                    \
    r0 = *(const float4*)(py0);                    \
    rr = *(const float4*)(pyr);                    \
    px += sx; pyl += sl; py0 += so; pyr += sr;

#define FMABLK(rx, rl, r0, rr) {                                          \
    const float yw[10] = { rl.y, rl.z, rl.w,                              \
                           r0.x, r0.y, r0.z, r0.w,                        \
                           rr.x, rr.y, rr.z };                            \
    const float xv[4]  = { rx.x, rx.y, rx.z, rx.w };                      \
    _Pragma("unroll")                                                     \
    for (int j = 0; j < Kq; ++j)                                          \
        _Pragma("unroll")                                                 \
        for (int r = 0; r < 4; ++r)                                       \
            acc[j][r] = fmaf(xv[r], yw[r + j], acc[j][r]);                \
}

    ISSUE(Ax, Ayl, Ay0, Ayr, axq, alq, aoq, arq)   // ch 0
    ISSUE(Bx, Byl, By0, Byr, bxq, blq, boq, brq)   // ch 1

#pragma unroll 1
    for (int c = 0; c < Cq - 2; c += 2) {
        FMABLK(axq, alq, aoq, arq)                       // consume ch c
        ISSUE(Ax, Ayl, Ay0, Ayr, axq, alq, aoq, arq)     // load ch c+2
        FMABLK(bxq, blq, boq, brq)                       // consume ch c+1
        ISSUE(Bx, Byl, By0, Byr, bxq, blq, boq, brq)     // load ch c+3
    }
    FMABLK(axq, alq, aoq, arq)   // ch 126
    FMABLK(bxq, blq, boq, brq)   // ch 127

#undef ISSUE
#undef FMABLK

    // epilogue: this wave writes k-planes wave*7 .. wave*7+6 (one quad each)
    size_t obase = (((size_t)b * (Kq * Kq) + (size_t)wave * Kq) * Hq
                    + (h0 + lr)) * Wq + wq;
#pragma unroll
    for (int j = 0; j < Kq; ++j) {
        float4 o = {acc[j][0], acc[j][1], acc[j][2], acc[j][3]};
        *(float4*)(out + obase) = o;
        obase += (size_t)CS;  // next k-plane
    }
}

extern "C" void kernel_launch(void* const* d_in, const int* in_sizes, int n_in,
                              void* d_out, int out_size, void* d_ws, size_t ws_size,
                              hipStream_t stream) {
    const float* x = (const float*)d_in[0];
    const float* y = (const float*)d_in[1];
    float* out = (float*)d_out;

    // zero pad-source region (invalid-lane pointers aim here, stride 0)
    hipMemsetAsync(d_ws, 0, 256, stream);

    dim3 grid(Bq * 32 * 8);   // 2048 tiles: 8 batches x 32 h x 8 w
    dim3 block(NTHR);
    hipLaunchKernelGGL(corr7_kernel, grid, block, 0, stream,
                       x, y, out, (const float*)d_ws);
}

// Round 6
// 382.644 us; speedup vs baseline: 7.1109x; 1.1092x over previous
//
#include <hip/hip_runtime.h>

// CorrNeigh: out[b, i*7+j, h, w] = sum_c x[b,c,h,w] * y[b,c,h+i-3,w+j-3]
// B=8 C=128 H=W=256, K=7, PAD=3, fp32.
//
// Round 6: R5 was latency-bound (VALUBusy 29%, HBM 19%) because the compiler
// targeted 64 VGPR and SANK the pipeline loads down to their consumers
// (legal: nothing pinned them). Fixes:
//  - asm volatile memory clobber after each issue-group: loads cannot sink
//    past a clobber -> in-flight values stay live -> pipeline survives.
//  - 4-deep rotating pipeline (128 channels % 4 == 0): ONE set of 4 rotating
//    pointers (8 VGPR), 4 in-flight quad-sets (64 VGPR), issue-to-use
//    distance ~200 cy/wave -> ~700 cy coverage at 3.5 waves/SIMD.
//  - __launch_bounds__(448) without the min-waves arg (the ",4" produced the
//    pathological 64-VGPR cap in R4/R5).
// Structure otherwise = R5 (passed): 7 waves = 7 dy, lane owns 4 pixels of a
// 32w x 8h tile; pad semantics via pointer redirect to zeroed d_ws with
// per-lane stride 0; no LDS/shfl/masks in the loop; XCD-chunked swizzle.

#define Bq 8
#define Cq 128
#define Hq 256
#define Wq 256
#define Kq 7
#define TILE_H 8
#define TILE_W 32
#define NTHR 448
#define CS (Hq * Wq)
#define DEPTH 4

__global__ __launch_bounds__(NTHR)
void corr7_kernel(const float* __restrict__ x, const float* __restrict__ y,
                  float* __restrict__ out, const float* __restrict__ zbuf)
{
    const int t    = threadIdx.x;
    const int wave = t >> 6;        // dy index i (0..6)
    const int lane = t & 63;
    const int lw   = lane & 7;      // w-quad (8 quads x 4 = 32 cols)
    const int lr   = lane >> 3;     // row within tile (0..7)

    // XCD-chunked swizzle: XCD k gets tiles [k*256, (k+1)*256) = one image
    int bid = (int)blockIdx.x;
    bid = (bid & 7) * 256 + (bid >> 3);
    const int tw = bid & 7;          // 8 w-tiles
    const int th = (bid >> 3) & 31;  // 32 h-tiles
    const int b  = bid >> 8;         // batch

    const int h0 = th * TILE_H;
    const int w0 = tw * TILE_W;
    const int wq = w0 + 4 * lw;      // this lane's first output column

    const size_t base = (size_t)b * Cq * CS;

    // validity (invalid -> zbuf with stride 0; pad reads return 0)
    const int gy  = h0 + lr + wave - 3;
    const bool vo = ((unsigned)gy < (unsigned)Hq);
    const bool vl = vo && !(tw == 0 && lw == 0);
    const bool vr = vo && !(tw == 7 && lw == 7);

    const float* yrow = y + base + (size_t)(vo ? gy : 0) * Wq;

    // rotating pointer set (one per stream), bumped by one channel per issue
    const float* px = x + base + (size_t)(h0 + lr) * Wq + wq;
    const float* po = vo ? (yrow + wq)     : zbuf;
    const float* pl = vl ? (yrow + wq - 4) : zbuf;
    const float* pr = vr ? (yrow + wq + 4) : zbuf;

    const unsigned so1 = vo ? (unsigned)CS : 0u;
    const unsigned sl1 = vl ? (unsigned)CS : 0u;
    const unsigned sr1 = vr ? (unsigned)CS : 0u;

    float acc[Kq][4];
#pragma unroll
    for (int j = 0; j < Kq; ++j)
#pragma unroll
        for (int r = 0; r < 4; ++r) acc[j][r] = 0.f;

    float4 fx[DEPTH], fl[DEPTH], fo[DEPTH], fr[DEPTH];

#define ISSUE(S)                                   \
    fx[S] = *(const float4*)px;                    \
    fl[S] = *(const float4*)pl;                    \
    fo[S] = *(const float4*)po;                    \
    fr[S] = *(const float4*)pr;                    \
    px += CS; pl += sl1; po += so1; pr += sr1;     \
    asm volatile("" ::: "memory");

#define FMABLK(S) {                                                       \
    const float yw[10] = { fl[S].y, fl[S].z, fl[S].w,                     \
                           fo[S].x, fo[S].y, fo[S].z, fo[S].w,            \
                           fr[S].x, fr[S].y, fr[S].z };                   \
    const float xv[4]  = { fx[S].x, fx[S].y, fx[S].z, fx[S].w };          \
    _Pragma("unroll")                                                     \
    for (int j = 0; j < Kq; ++j)                                          \
        _Pragma("unroll")                                                 \
        for (int r = 0; r < 4; ++r)                                       \
            acc[j][r] = fmaf(xv[r], yw[r + j], acc[j][r]);                \
}

    // prologue: fill the 4-deep pipeline (channels 0..3)
#pragma unroll
    for (int s = 0; s < DEPTH; ++s) { ISSUE(s) }

    // steady state: 31 iterations x 4 channels = channels 0..123 consumed,
    // issues run to channel 127 exactly.
#pragma unroll 1
    for (int c = 0; c < Cq - DEPTH; c += DEPTH) {
#pragma unroll
        for (int s = 0; s < DEPTH; ++s) {
            FMABLK(s)
            ISSUE(s)
        }
    }
    // epilogue: drain channels 124..127
#pragma unroll
    for (int s = 0; s < DEPTH; ++s) { FMABLK(s) }

#undef ISSUE
#undef FMABLK

    // this wave writes k-planes wave*7 .. wave*7+6 (one quad each)
    size_t obase = (((size_t)b * (Kq * Kq) + (size_t)wave * Kq) * Hq
                    + (h0 + lr)) * Wq + wq;
#pragma unroll
    for (int j = 0; j < Kq; ++j) {
        float4 o = {acc[j][0], acc[j][1], acc[j][2], acc[j][3]};
        *(float4*)(out + obase) = o;
        obase += (size_t)CS;  // next k-plane
    }
}

extern "C" void kernel_launch(void* const* d_in, const int* in_sizes, int n_in,
                              void* d_out, int out_size, void* d_ws, size_t ws_size,
                              hipStream_t stream) {
    const float* x = (const float*)d_in[0];
    const float* y = (const float*)d_in[1];
    float* out = (float*)d_out;

    // zero pad-source region (invalid-lane pointers aim here, stride 0)
    hipMemsetAsync(d_ws, 0, 256, stream);

    dim3 grid(Bq * 32 * 8);   // 2048 tiles: 8 batches x 32 h x 8 w
    dim3 block(NTHR);
    hipLaunchKernelGGL(corr7_kernel, grid, block, 0, stream,
                       x, y, out, (const float*)d_ws);
}